// Round 2
// baseline (623.340 us; speedup 1.0000x reference)
//
#include <hip/hip_runtime.h>
#include <cmath>

// ---------------- problem constants ----------------
constexpr int NUSER = 100000;
constexpr int NNEWS = 20000;
constexpr int CH    = 128;
constexpr int NE    = 250000;
constexpr int NTOT  = NNEWS + NUSER + NUSER;   // joint counter array (rel0|rel1|rel2)
constexpr int NSB   = (NTOT + 255) / 256;      // scan blocks = 860

typedef _Float16 f16x8 __attribute__((ext_vector_type(8)));
typedef _Float16 f16x4 __attribute__((ext_vector_type(4)));
typedef _Float16 f16x2 __attribute__((ext_vector_type(2)));
typedef float    f32x4 __attribute__((ext_vector_type(4)));

// ---------------- workspace layout (float units) ----------------
constexpr size_t OFF_QU  = 0;                                   // q_user fp16 [NUSER*128]
constexpr size_t OFF_QN  = OFF_QU  + (size_t)NUSER * 64;        // q_news fp16
constexpr size_t OFF_AGU = OFF_QN  + (size_t)NNEWS * 64;        // agg_user fp16 (gelu'd)
constexpr size_t OFF_AGN = OFF_AGU + (size_t)NUSER * 64;        // agg_news fp16 (gelu'd)
constexpr size_t OFF_KVB = OFF_AGN + (size_t)NNEWS * 64;        // kv_big fp16 [NUSER][256] (k|v interleaved)
constexpr size_t OFF_KVS = OFF_KVB + (size_t)NUSER * 128;       // kv_sm  fp16 [NNEWS][256]
constexpr size_t OFF_WF  = OFF_KVS + (size_t)NNEWS * 128;       // swizzled fp16 frags, BOTH layers (20 matrices)
constexpr size_t OFF_BE  = OFF_WF  + 20 * 8192;                 // bke[2][3][128] + bve[2][3][128] f32
constexpr size_t OFF_INT = OFF_BE  + 2 * 768;
// int offsets (relative, units: int)
constexpr size_t IO_CU   = 0;                    // joint counters [NTOT]
constexpr size_t IO_JRP  = IO_CU  + NTOT;        // joint row_ptr [NTOT+1]
constexpr size_t IO_BSUM = IO_JRP + NTOT + 1;    // scan partials [NSB]
constexpr size_t IO_BOFF = IO_BSUM + NSB;        // scan offsets  [NSB]
constexpr size_t IO_CL   = IO_BOFF + NSB;        // col (src per CSR slot) [3*NE]
constexpr size_t IO_RANK = IO_CL + 3 * NE;       // per-edge rank within dst [3*NE]

__device__ __forceinline__ float gelu_f(float x) {
    return 0.5f * x * (1.0f + erff(x * 0.70710678118654752440f));
}

// ---------------- swizzled-fragment dest index ----------------
// MFMA 16x16x32 fragment (lane,j): idx = lane&15, k = (lane>>4)*8 + j.
// Wf layout: [kt][ct][lane][j] contiguous -> coalesced b128 stage, conflict-free ds_read_b128.
__device__ __forceinline__ int frag_dest(int k, int col) {
    int kt = k >> 5, quad = (k >> 3) & 3, j = k & 7;
    int ct = col >> 4, m = col & 15;
    int lane = quad * 16 + m;
    return ((kt * 8 + ct) * 64 + lane) * 8 + j;
}

// ---------------- flat weight prep (both layers) + counter zeroing, one dispatch ----------------
constexpr int NEFF = 2 * 2 * 3 * 16384;   // 196608
constexpr int NCVT = 2 * 4 * 16384;       // 131072
constexpr int NBIA = 2 * 2 * 3 * 128;     // 1536
constexpr int NPREP = NEFF + NCVT + NBIA;

__global__ __launch_bounds__(256) void prep_weights_kernel(
    const float* __restrict__ Wk, const float* __restrict__ bk,
    const float* __restrict__ Wv, const float* __restrict__ bv,
    const float* __restrict__ Wq, const float* __restrict__ Wa,
    const float* __restrict__ a_rel, const float* __restrict__ m_rel,
    const float* __restrict__ p_rel,
    _Float16* __restrict__ wkf, float* __restrict__ bke,
    _Float16* __restrict__ wvf, float* __restrict__ bve,
    _Float16* __restrict__ wqf, _Float16* __restrict__ waf,
    int* __restrict__ cu)
{
    const float kscale = 0.17677669529663688f * 1.44269504088896340f;  // 1/sqrt(32)*log2(e)
    int idx = blockIdx.x * 256 + threadIdx.x;
    if (idx < NEFF) {
        int o = idx & 16383;
        int g = idx >> 14;          // (l*2+kind)*3 + r
        int r = g % 3, lk = g / 3, kind = lk & 1, l = lk >> 1;
        int st = (r == 1) ? 1 : 0;
        const float* W   = (kind ? Wv : Wk) + ((size_t)(l * 2 + st)) * 16384;
        const float* rel = (kind ? m_rel : a_rel) + ((size_t)(l * 3 + r)) * 4096;
        _Float16* Wf = (kind ? wvf : wkf) + ((size_t)(l * 3 + r)) * 16384;
        int k = o >> 7, col = o & 127, h = col >> 5, e = col & 31;
        const float* wrow = W + (size_t)k * 128 + h * 32;
        const float* rcol = rel + h * 1024 + e;
        float s = 0.f;
        #pragma unroll
        for (int d = 0; d < 32; ++d) s += wrow[d] * rcol[d * 32];
        if (kind == 0) s *= p_rel[(l * 3 + r) * 4 + h] * kscale;
        Wf[frag_dest(k, col)] = (_Float16)s;
    } else if (idx < NEFF + NCVT) {
        int t = idx - NEFF;
        int o = t & 16383;
        int b = t >> 14;            // l*4 + sub  (sub 0,1: Wq types; 2,3: Wa types)
        int l = b >> 2, sub = b & 3;
        const float* W;
        _Float16* Wf;
        if (sub < 2) { W = Wq + ((size_t)(l * 2 + sub)) * 16384;     Wf = wqf + ((size_t)(l * 2 + sub)) * 16384; }
        else         { W = Wa + ((size_t)(l * 2 + sub - 2)) * 16384; Wf = waf + ((size_t)(l * 2 + sub - 2)) * 16384; }
        int k = o >> 7, col = o & 127;
        Wf[frag_dest(k, col)] = (_Float16)W[o];
    } else if (idx < NPREP) {
        int t = idx - NEFF - NCVT;
        int col = t & 127;
        int g = t >> 7;
        int r = g % 3, lk = g / 3, kind = lk & 1, l = lk >> 1;
        int st = (r == 1) ? 1 : 0;
        const float* bi  = (kind ? bv : bk) + ((size_t)(l * 2 + st)) * 128;
        const float* rel = (kind ? m_rel : a_rel) + ((size_t)(l * 3 + r)) * 4096;
        float* be = (kind ? bve : bke) + (size_t)l * 384 + r * 128;
        int h = col >> 5, e = col & 31;
        float s = 0.f;
        #pragma unroll
        for (int d = 0; d < 32; ++d) s += bi[h * 32 + d] * rel[h * 1024 + d * 32 + e];
        if (kind == 0) s *= p_rel[(l * 3 + r) * 4 + h] * kscale;
        be[col] = s;
    } else if (idx < NPREP + NTOT) {
        cu[idx - NPREP] = 0;       // zero the CSR counters (fused: saves a dispatch)
    }
}

// ---------------- CSR build: hist + per-edge rank (atomics), scan, atomic-free fill ----------------
__global__ void histrank_kernel(const int* __restrict__ e0, const int* __restrict__ e1,
                                const int* __restrict__ e2, int* __restrict__ cu,
                                int* __restrict__ rank) {
    int idx = blockIdx.x * 256 + threadIdx.x;
    if (idx >= 3 * NE) return;
    int r = idx / NE, e = idx - r * NE;
    const int* ei = (r == 0) ? e0 : (r == 1) ? e1 : e2;
    int base = (r == 0) ? 0 : (r == 1) ? NNEWS : (NNEWS + NUSER);
    rank[idx] = atomicAdd(&cu[base + ei[NE + e]], 1);
}

__global__ __launch_bounds__(256) void scan_part_kernel(const int* __restrict__ cu,
                                                        int* __restrict__ bsum) {
    int i = blockIdx.x * 256 + threadIdx.x;
    int v = (i < NTOT) ? cu[i] : 0;
    #pragma unroll
    for (int o = 1; o < 64; o <<= 1) v += __shfl_xor(v, o);
    __shared__ int ws_[4];
    if ((threadIdx.x & 63) == 0) ws_[threadIdx.x >> 6] = v;
    __syncthreads();
    if (threadIdx.x == 0) bsum[blockIdx.x] = ws_[0] + ws_[1] + ws_[2] + ws_[3];
}

__global__ __launch_bounds__(1024) void scan_top_kernel(const int* __restrict__ bsum,
                                                        int* __restrict__ boff,
                                                        int* __restrict__ jrp) {
    __shared__ int wsum[16];
    int tid = threadIdx.x, lane = tid & 63, w = tid >> 6;
    int v = (tid < NSB) ? bsum[tid] : 0;
    int x = v;
    #pragma unroll
    for (int o = 1; o < 64; o <<= 1) { int y = __shfl_up(x, o); if (lane >= o) x += y; }
    if (lane == 63) wsum[w] = x;
    __syncthreads();
    if (tid < 16) {
        int t = wsum[tid];
        #pragma unroll
        for (int o = 1; o < 16; o <<= 1) { int y = __shfl_up(t, o); if (tid >= o) t += y; }
        wsum[tid] = t;
    }
    __syncthreads();
    int woff = w ? wsum[w - 1] : 0;
    if (tid < NSB) boff[tid] = woff + x - v;
    if (tid == 0) jrp[NTOT] = 3 * NE;
}

__global__ __launch_bounds__(256) void scan_fin_kernel(const int* __restrict__ cu,
                                                       const int* __restrict__ boff,
                                                       int* __restrict__ jrp) {
    __shared__ int wsum[4];
    int tid = threadIdx.x, lane = tid & 63, w = tid >> 6;
    int i = blockIdx.x * 256 + tid;
    int v = (i < NTOT) ? cu[i] : 0;
    int x = v;
    #pragma unroll
    for (int o = 1; o < 64; o <<= 1) { int y = __shfl_up(x, o); if (lane >= o) x += y; }
    if (lane == 63) wsum[w] = x;
    __syncthreads();
    int woff = 0;
    #pragma unroll
    for (int k = 0; k < 4; ++k) if (k < w) woff += wsum[k];
    int excl = boff[blockIdx.x] + woff + x - v;
    if (i < NTOT) jrp[i] = excl;
}

__global__ void fill_kernel(const int* __restrict__ e0, const int* __restrict__ e1,
                            const int* __restrict__ e2, const int* __restrict__ jrp,
                            const int* __restrict__ rank, int* __restrict__ cl) {
    int idx = blockIdx.x * 256 + threadIdx.x;
    if (idx >= 3 * NE) return;
    int r = idx / NE, e = idx - r * NE;
    const int* ei = (r == 0) ? e0 : (r == 1) ? e1 : e2;
    int base = (r == 0) ? 0 : (r == 1) ? NNEWS : (NNEWS + NUSER);
    int dst = ei[NE + e], src = ei[e];
    cl[jrp[base + dst] + rank[idx]] = src;   // no atomics (R8: fill3 = 46 us of atomic latency)
}

// ---------------- MFMA GEMM v5: LDS weights + software-pipelined T-tile loop ----------------
// Changes vs v4 (R1 theory: per-tile x loads exposed ~900cy HBM latency at only 8 waves/CU):
//  - tile-0 x loads issued BEFORE the LDS weight stage + barrier (hides under staging)
//  - x double-buffered in named registers: tile t+1's loads issued before tile t's MFMAs
//  - T is a template parameter, loop fully unrolled -> all buffer refs static (no scratch)
//  - SKIP epilogue's Xold loaded at tile start (hides under the MFMA chain)
template<int NOUT, int T, bool IN_HALF, bool GELU_IN, bool SKIP_OUT, bool OUT_HALF>
__global__ __launch_bounds__(256) void gemm_v5(
    const void* __restrict__ Ain,
    const _Float16* __restrict__ Wf0, const _Float16* __restrict__ Wf1,
    const float* __restrict__ b0, const float* __restrict__ b1,
    void* __restrict__ out0, void* __restrict__ out1, int ostride,
    int N, const float* __restrict__ skipv, const float* __restrict__ Xold)
{
    __shared__ _Float16 sW[NOUT * 16384];   // 32 KB per weight matrix
    const int tid = threadIdx.x;
    const int lane = tid & 63;
    const int m = lane & 15, quad = lane >> 4, wave = tid >> 6;
    const int base_row = blockIdx.x * T * 64;

    // named double buffers (never runtime-indexed -> stay in VGPRs)
    f32x4 xc32_0, xc32_1, xc32_2, xc32_3, xc32_4, xc32_5, xc32_6, xc32_7;
    f32x4 xn32_0, xn32_1, xn32_2, xn32_3, xn32_4, xn32_5, xn32_6, xn32_7;
    f16x8 xc16_0, xc16_1, xc16_2, xc16_3;
    f16x8 xn16_0, xn16_1, xn16_2, xn16_3;

#define LOADX_NEXT(tt)                                                              \
    do {                                                                            \
        int node_ = base_row + (tt) * 64 + wave * 16 + m;                           \
        if (node_ > N - 1) node_ = N - 1;                                           \
        if constexpr (IN_HALF) {                                                    \
            const _Float16* A_ = (const _Float16*)Ain + (size_t)node_ * 128 + quad * 8; \
            xn16_0 = *(const f16x8*)(A_);                                           \
            xn16_1 = *(const f16x8*)(A_ + 32);                                      \
            xn16_2 = *(const f16x8*)(A_ + 64);                                      \
            xn16_3 = *(const f16x8*)(A_ + 96);                                      \
        } else {                                                                    \
            const float* A_ = (const float*)Ain + (size_t)node_ * 128 + quad * 8;   \
            xn32_0 = *(const f32x4*)(A_);        xn32_1 = *(const f32x4*)(A_ + 4);  \
            xn32_2 = *(const f32x4*)(A_ + 32);   xn32_3 = *(const f32x4*)(A_ + 36); \
            xn32_4 = *(const f32x4*)(A_ + 64);   xn32_5 = *(const f32x4*)(A_ + 68); \
            xn32_6 = *(const f32x4*)(A_ + 96);   xn32_7 = *(const f32x4*)(A_ + 100);\
        }                                                                           \
    } while (0)

#define ROTATE_X()                                                                  \
    do {                                                                            \
        if constexpr (IN_HALF) {                                                    \
            xc16_0 = xn16_0; xc16_1 = xn16_1; xc16_2 = xn16_2; xc16_3 = xn16_3;     \
        } else {                                                                    \
            xc32_0 = xn32_0; xc32_1 = xn32_1; xc32_2 = xn32_2; xc32_3 = xn32_3;     \
            xc32_4 = xn32_4; xc32_5 = xn32_5; xc32_6 = xn32_6; xc32_7 = xn32_7;     \
        }                                                                           \
    } while (0)

    // tile-0 x prefetch, issued before LDS staging so HBM latency hides under it
    LOADX_NEXT(0);
    ROTATE_X();

    for (int i = tid; i < NOUT * 2048; i += 256) {
        const _Float16* src = (NOUT == 1 || i < 2048) ? (Wf0 + (size_t)i * 8)
                                                      : (Wf1 + (size_t)(i - 2048) * 8);
        *(f16x8*)(sW + (size_t)i * 8) = *(const f16x8*)src;
    }
    __syncthreads();

    float aS = 0.f, bSk = 0.f;
    if constexpr (SKIP_OUT) {
        float sv = skipv[0];
        aS = 1.0f / (1.0f + expf(-sv));
        bSk = 1.0f - aS;
    }

    #pragma unroll
    for (int t = 0; t < T; ++t) {
        const int row0 = base_row + t * 64;
        if (row0 >= N) break;                       // block-uniform (no barriers inside)
        const int node  = row0 + wave * 16 + m;
        const int nodec = (node < N) ? node : (N - 1);

        // issue NEXT tile's x loads before this tile's compute
        if (t + 1 < T) LOADX_NEXT(t + 1);

        // skip-path residual, loaded early so it completes under the MFMAs
        f32x4 xo0, xo1, xo2, xo3, xo4, xo5, xo6, xo7;
        if constexpr (SKIP_OUT) {
            const float* Xo = Xold + (size_t)nodec * 128 + quad * 4;
            xo0 = *(const f32x4*)(Xo);       xo1 = *(const f32x4*)(Xo + 16);
            xo2 = *(const f32x4*)(Xo + 32);  xo3 = *(const f32x4*)(Xo + 48);
            xo4 = *(const f32x4*)(Xo + 64);  xo5 = *(const f32x4*)(Xo + 80);
            xo6 = *(const f32x4*)(Xo + 96);  xo7 = *(const f32x4*)(Xo + 112);
        }

        // convert current x to MFMA B-frags
        f16x8 xf[4];
        if constexpr (IN_HALF) {
            xf[0] = xc16_0; xf[1] = xc16_1; xf[2] = xc16_2; xf[3] = xc16_3;
            if constexpr (GELU_IN) {
                #pragma unroll
                for (int kt = 0; kt < 4; ++kt)
                    #pragma unroll
                    for (int j = 0; j < 8; ++j) xf[kt][j] = (_Float16)gelu_f((float)xf[kt][j]);
            }
        } else {
            f32x4 a0[4] = {xc32_0, xc32_2, xc32_4, xc32_6};
            f32x4 a1[4] = {xc32_1, xc32_3, xc32_5, xc32_7};
            #pragma unroll
            for (int kt = 0; kt < 4; ++kt) {
                f32x4 u = a0[kt], v = a1[kt];
                if constexpr (GELU_IN) {
                    #pragma unroll
                    for (int j = 0; j < 4; ++j) { u[j] = gelu_f(u[j]); v[j] = gelu_f(v[j]); }
                }
                xf[kt] = (f16x8){(_Float16)u[0], (_Float16)u[1], (_Float16)u[2], (_Float16)u[3],
                                 (_Float16)v[0], (_Float16)v[1], (_Float16)v[2], (_Float16)v[3]};
            }
        }

        f32x4 acc0[8], acc1[8];
        #pragma unroll
        for (int u = 0; u < 8; ++u) {
            acc0[u] = (f32x4){0.f, 0.f, 0.f, 0.f};
            if constexpr (NOUT > 1) acc1[u] = (f32x4){0.f, 0.f, 0.f, 0.f};
        }

        #pragma unroll
        for (int kt = 0; kt < 4; ++kt) {
            #pragma unroll
            for (int ct = 0; ct < 8; ++ct) {
                f16x8 wf0 = *(const f16x8*)(sW + ((kt * 8 + ct) * 64 + lane) * 8);
                acc0[ct] = __builtin_amdgcn_mfma_f32_16x16x32_f16(wf0, xf[kt], acc0[ct], 0, 0, 0);
                if constexpr (NOUT > 1) {
                    f16x8 wf1 = *(const f16x8*)(sW + 16384 + ((kt * 8 + ct) * 64 + lane) * 8);
                    acc1[ct] = __builtin_amdgcn_mfma_f32_16x16x32_f16(wf1, xf[kt], acc1[ct], 0, 0, 0);
                }
            }
        }

        if (node < N) {
            f32x4 xoa[8];
            if constexpr (SKIP_OUT) {
                xoa[0] = xo0; xoa[1] = xo1; xoa[2] = xo2; xoa[3] = xo3;
                xoa[4] = xo4; xoa[5] = xo5; xoa[6] = xo6; xoa[7] = xo7;
            }
            #pragma unroll
            for (int ct = 0; ct < 8; ++ct) {
                int c = ct * 16 + quad * 4;      // out-channel base for this lane's 4 regs
                {
                    f32x4 r = acc0[ct] + *(const f32x4*)(b0 + c);
                    if constexpr (SKIP_OUT) {
                        #pragma unroll
                        for (int j = 0; j < 4; ++j) r[j] = fmaxf(aS * r[j] + bSk * xoa[ct][j], 0.f);
                    }
                    if constexpr (OUT_HALF) {
                        f16x4 h = {(_Float16)r[0], (_Float16)r[1], (_Float16)r[2], (_Float16)r[3]};
                        *(f16x4*)((_Float16*)out0 + (size_t)node * ostride + c) = h;
                    } else {
                        *(f32x4*)((float*)out0 + (size_t)node * ostride + c) = r;
                    }
                }
                if constexpr (NOUT > 1) {
                    f32x4 r = acc1[ct] + *(const f32x4*)(b1 + c);
                    f16x4 h = {(_Float16)r[0], (_Float16)r[1], (_Float16)r[2], (_Float16)r[3]};
                    *(f16x4*)((_Float16*)out1 + (size_t)node * ostride + c) = h;
                }
            }
        }

        if (t + 1 < T) ROTATE_X();
    }
#undef LOADX_NEXT
#undef ROTATE_X
}

// ---------------- attention v5 (reverted from v6: 4-slot clamp-unroll REGRESSED 48->53us;
// kernel is VALU-issue-bound at ~64% busy, wasted clamp slots added issue work) ----------------
// kv interleaved [node][k|v] fp16. Lane sub (0..15): channels sub*8..+7, head = sub>>2.
// w = exp2(score) (log2e folded into k_eff). agg := gelu(softmax-agg)  [epilogue GEMM eats it raw].
__global__ __launch_bounds__(256) void attn_v5(
    const _Float16* __restrict__ q,
    const _Float16* __restrict__ kv1, const int* __restrict__ rp1,
    const _Float16* __restrict__ kv2, const int* __restrict__ rp2,
    const int* __restrict__ cl,
    _Float16* __restrict__ agg, int Ndst, int two)
{
    int d = blockIdx.x * 16 + (threadIdx.x >> 4);   // 16 nodes per block (4 per wave)
    if (d >= Ndst) return;
    const int sub = threadIdx.x & 15;
    f16x8 qh = *(const f16x8*)(q + (size_t)d * 128 + sub * 8);
    float acc[8] = {0.f, 0.f, 0.f, 0.f, 0.f, 0.f, 0.f, 0.f};

    for (int rel = 0; rel < 1 + two; ++rel) {
        const _Float16* kv = rel ? kv2 : kv1;
        const int* rp = rel ? rp2 : rp1;
        int e0 = rp[d], e1 = rp[d + 1];
        float den = 0.f;
        float s[8] = {0.f, 0.f, 0.f, 0.f, 0.f, 0.f, 0.f, 0.f};
        int e = e0;
        for (; e + 1 < e1; e += 2) {                // two independent chains per iter
            int s0 = cl[e], s1 = cl[e + 1];
            const _Float16* r0 = kv + (size_t)s0 * 256;
            const _Float16* r1 = kv + (size_t)s1 * 256;
            f16x8 k0 = *(const f16x8*)(r0 + sub * 8);
            f16x8 v0 = *(const f16x8*)(r0 + 128 + sub * 8);
            f16x8 k1 = *(const f16x8*)(r1 + sub * 8);
            f16x8 v1 = *(const f16x8*)(r1 + 128 + sub * 8);
            float p0 = 0.f, p1 = 0.f;
#if __has_builtin(__builtin_amdgcn_fdot2)
            const f16x2* qp = (const f16x2*)&qh;
            const f16x2* a0 = (const f16x2*)&k0;
            const f16x2* a1 = (const f16x2*)&k1;
            #pragma unroll
            for (int j = 0; j < 4; ++j) {
                p0 = __builtin_amdgcn_fdot2(a0[j], qp[j], p0, false);
                p1 = __builtin_amdgcn_fdot2(a1[j], qp[j], p1, false);
            }
#else
            #pragma unroll
            for (int j = 0; j < 8; ++j) {
                p0 += (float)k0[j] * (float)qh[j];
                p1 += (float)k1[j] * (float)qh[j];
            }
#endif
            p0 += __shfl_xor(p0, 1); p1 += __shfl_xor(p1, 1);
            p0 += __shfl_xor(p0, 2); p1 += __shfl_xor(p1, 2);
            float w0 = exp2f(p0), w1 = exp2f(p1);
            den += w0 + w1;
            #pragma unroll
            for (int j = 0; j < 8; ++j) s[j] += w0 * (float)v0[j] + w1 * (float)v1[j];
        }
        if (e < e1) {
            int s0 = cl[e];
            const _Float16* r0 = kv + (size_t)s0 * 256;
            f16x8 k0 = *(const f16x8*)(r0 + sub * 8);
            f16x8 v0 = *(const f16x8*)(r0 + 128 + sub * 8);
            float p0 = 0.f;
#if __has_builtin(__builtin_amdgcn_fdot2)
            const f16x2* qp = (const f16x2*)&qh;
            const f16x2* a0 = (const f16x2*)&k0;
            #pragma unroll
            for (int j = 0; j < 4; ++j) p0 = __builtin_amdgcn_fdot2(a0[j], qp[j], p0, false);
#else
            #pragma unroll
            for (int j = 0; j < 8; ++j) p0 += (float)k0[j] * (float)qh[j];
#endif
            p0 += __shfl_xor(p0, 1);
            p0 += __shfl_xor(p0, 2);
            float w0 = exp2f(p0);
            den += w0;
            #pragma unroll
            for (int j = 0; j < 8; ++j) s[j] += w0 * (float)v0[j];
        }
        if (den > 0.f) {
            float inv = 1.f / den;
            #pragma unroll
            for (int j = 0; j < 8; ++j) acc[j] += s[j] * inv;
        }
    }

    f16x8 o;
    #pragma unroll
    for (int j = 0; j < 8; ++j) o[j] = (_Float16)gelu_f(acc[j]);   // gelu fused (epilogue is pure MFMA)
    *(f16x8*)(agg + (size_t)d * 128 + sub * 8) = o;
}

// ---------------- orchestration ----------------
extern "C" void kernel_launch(void* const* d_in, const int* in_sizes, int n_in,
                              void* d_out, int out_size, void* d_ws, size_t ws_size,
                              hipStream_t stream)
{
    const float* x_user = (const float*)d_in[0];
    const float* x_news = (const float*)d_in[1];
    const int* ei0 = (const int*)d_in[2];
    const int* ei1 = (const int*)d_in[3];
    const int* ei2 = (const int*)d_in[4];
    const float* Wk = (const float*)d_in[5];
    const float* bk = (const float*)d_in[6];
    const float* Wq = (const float*)d_in[7];
    const float* bq = (const float*)d_in[8];
    const float* Wv = (const float*)d_in[9];
    const float* bv = (const float*)d_in[10];
    const float* Wa = (const float*)d_in[11];
    const float* ba = (const float*)d_in[12];
    const float* skip = (const float*)d_in[13];
    const float* a_rel = (const float*)d_in[14];
    const float* m_rel = (const float*)d_in[15];
    const float* p_rel = (const float*)d_in[16];

    float* ws = (float*)d_ws;
    _Float16* q_user  = (_Float16*)(ws + OFF_QU);
    _Float16* q_news  = (_Float16*)(ws + OFF_QN);
    _Float16* agg_u   = (_Float16*)(ws + OFF_AGU);
    _Float16* agg_n   = (_Float16*)(ws + OFF_AGN);
    _Float16* kv_big  = (_Float16*)(ws + OFF_KVB);
    _Float16* kv_sm   = (_Float16*)(ws + OFF_KVS);
    _Float16* wkf = (_Float16*)(ws + OFF_WF);       // [2][3] matrices
    _Float16* wvf = wkf + 6 * 16384;                // [2][3]
    _Float16* wqf = wvf + 6 * 16384;                // [2][2]
    _Float16* waf = wqf + 4 * 16384;                // [2][2]
    float* bke = ws + OFF_BE;                       // [2][3][128]
    float* bve = bke + 768;
    int* ib   = (int*)(ws + OFF_INT);
    int* cu   = ib + IO_CU;
    int* jrp  = ib + IO_JRP;
    int* bsum = ib + IO_BSUM;
    int* boff = ib + IO_BOFF;
    int* cl   = ib + IO_CL;
    int* rank = ib + IO_RANK;
    const int* rp0 = jrp;
    const int* rp1 = jrp + NNEWS;
    const int* rp2 = jrp + NNEWS + NUSER;

    // ---- weight prep (both layers) + counter zero, one flat dispatch ----
    prep_weights_kernel<<<(NPREP + NTOT + 255) / 256, 256, 0, stream>>>(
        Wk, bk, Wv, bv, Wq, Wa, a_rel, m_rel, p_rel,
        wkf, bke, wvf, bve, wqf, waf, cu);

    // ---- CSR build: hist+rank (atomics) -> scan -> atomic-free fill ----
    int g3e = (3 * NE + 255) / 256;
    histrank_kernel<<<g3e, 256, 0, stream>>>(ei0, ei1, ei2, cu, rank);
    scan_part_kernel<<<NSB, 256, 0, stream>>>(cu, bsum);
    scan_top_kernel<<<1, 1024, 0, stream>>>(bsum, boff, jrp);
    scan_fin_kernel<<<NSB, 256, 0, stream>>>(cu, boff, jrp);
    fill_kernel<<<g3e, 256, 0, stream>>>(ei0, ei1, ei2, jrp, rank, cl);

    float* out_user = (float*)d_out;
    float* out_news = (float*)d_out + (size_t)NUSER * CH;

    constexpr int T1 = 2;   // NOUT=1 user GEMMs: 782 blocks (~3/CU)
    constexpr int T2 = 4;   // NOUT=2 user GEMMs: 64KB LDS caps 2 blocks/CU anyway
    int gbU1 = (NUSER + 64 * T1 - 1) / (64 * T1);
    int gbU2 = (NUSER + 64 * T2 - 1) / (64 * T2);
    int gbN  = (NNEWS + 63) / 64;                  // news: T=1 (keep TLP)

    for (int l = 0; l < 2; ++l) {
        const float* xu = l ? (const float*)out_user : x_user;
        const float* xn = l ? (const float*)out_news : x_news;
        _Float16* wkf_l = wkf + (size_t)l * 3 * 16384;
        _Float16* wvf_l = wvf + (size_t)l * 3 * 16384;
        _Float16* wqf_l = wqf + (size_t)l * 2 * 16384;
        _Float16* waf_l = waf + (size_t)l * 2 * 16384;
        float* bke_l = bke + (size_t)l * 384;
        float* bve_l = bve + (size_t)l * 384;

        // q projections (fp16, stride 128)
        gemm_v5<1, T1, false, false, false, true><<<gbU1, 256, 0, stream>>>(
            xu, wqf_l, nullptr, bq + (size_t)(l * 2 + 0) * 128, nullptr,
            q_user, nullptr, 128, NUSER, nullptr, nullptr);
        gemm_v5<1, 1, false, false, false, true><<<gbN, 256, 0, stream>>>(
            xn, wqf_l + 16384, nullptr, bq + (size_t)(l * 2 + 1) * 128, nullptr,
            q_news, nullptr, 128, NNEWS, nullptr, nullptr);

        // rel0 K/V (user src) -> kv_big, then news attention
        gemm_v5<2, T2, false, false, false, true><<<gbU2, 256, 0, stream>>>(
            xu, wkf_l, wvf_l, bke_l, bve_l,
            kv_big, kv_big + 128, 256, NUSER, nullptr, nullptr);
        attn_v5<<<(NNEWS + 15) / 16, 256, 0, stream>>>(
            q_news, kv_big, rp0, nullptr, nullptr, cl, agg_n, NNEWS, 0);

        // rel1 K/V (news src) -> kv_sm ; rel2 K/V (user src) -> kv_big (reuse, stream-ordered)
        gemm_v5<2, 1, false, false, false, true><<<gbN, 256, 0, stream>>>(
            xn, wkf_l + 16384, wvf_l + 16384, bke_l + 128, bve_l + 128,
            kv_sm, kv_sm + 128, 256, NNEWS, nullptr, nullptr);
        gemm_v5<2, T2, false, false, false, true><<<gbU2, 256, 0, stream>>>(
            xu, wkf_l + 32768, wvf_l + 32768, bke_l + 256, bve_l + 256,
            kv_big, kv_big + 128, 256, NUSER, nullptr, nullptr);
        attn_v5<<<(NUSER + 15) / 16, 256, 0, stream>>>(
            q_user, kv_sm, rp1, kv_big, rp2, cl, agg_u, NUSER, 1);

        // output transform: relu(sig(skip)*(gelu_agg@Wa + ba) + (1-sig)*x)  [gelu already in agg]
        gemm_v5<1, T1, true, false, true, false><<<gbU1, 256, 0, stream>>>(
            agg_u, waf_l, nullptr, ba + (size_t)(l * 2 + 0) * 128, nullptr,
            out_user, nullptr, 128, NUSER, skip + l * 2 + 0, xu);
        gemm_v5<1, 1, true, false, true, false><<<gbN, 256, 0, stream>>>(
            agg_n, waf_l + 16384, nullptr, ba + (size_t)(l * 2 + 1) * 128, nullptr,
            out_news, nullptr, 128, NNEWS, skip + l * 2 + 1, xn);
    }
    (void)in_sizes; (void)n_in; (void)out_size; (void)ws_size;
}

// Round 3
// 602.689 us; speedup vs baseline: 1.0343x; 1.0343x over previous
//
#include <hip/hip_runtime.h>
#include <cmath>

// ---------------- problem constants ----------------
constexpr int NUSER = 100000;
constexpr int NNEWS = 20000;
constexpr int CH    = 128;
constexpr int NE    = 250000;
constexpr int NTOT  = NNEWS + NUSER + NUSER;   // joint counter array (rel0|rel1|rel2)
constexpr int NSB   = (NTOT + 255) / 256;      // scan blocks = 860

typedef _Float16 f16x8 __attribute__((ext_vector_type(8)));
typedef _Float16 f16x4 __attribute__((ext_vector_type(4)));
typedef _Float16 f16x2 __attribute__((ext_vector_type(2)));
typedef float    f32x4 __attribute__((ext_vector_type(4)));

// ---------------- workspace layout (float units) ----------------
constexpr size_t OFF_QU  = 0;                                   // q_user fp16 [NUSER*128]
constexpr size_t OFF_QN  = OFF_QU  + (size_t)NUSER * 64;        // q_news fp16
constexpr size_t OFF_AGU = OFF_QN  + (size_t)NNEWS * 64;        // agg_user fp16 (gelu'd)
constexpr size_t OFF_AGN = OFF_AGU + (size_t)NUSER * 64;        // agg_news fp16 (gelu'd)
constexpr size_t OFF_KVB = OFF_AGN + (size_t)NNEWS * 64;        // kv_big fp16 [NUSER][256] (k|v interleaved)
constexpr size_t OFF_KVS = OFF_KVB + (size_t)NUSER * 128;       // kv_sm  fp16 [NNEWS][256]
constexpr size_t OFF_WF  = OFF_KVS + (size_t)NNEWS * 128;       // swizzled fp16 frags, BOTH layers (20 matrices)
constexpr size_t OFF_BE  = OFF_WF  + 20 * 8192;                 // bke[2][3][128] + bve[2][3][128] f32
constexpr size_t OFF_INT = OFF_BE  + 2 * 768;
// int offsets (relative, units: int)
constexpr size_t IO_CU   = 0;                    // joint counters [NTOT]
constexpr size_t IO_JRP  = IO_CU  + NTOT;        // joint row_ptr [NTOT+1]
constexpr size_t IO_BSUM = IO_JRP + NTOT + 1;    // scan partials [NSB]
constexpr size_t IO_BOFF = IO_BSUM + NSB;        // scan offsets  [NSB]
constexpr size_t IO_CL   = IO_BOFF + NSB;        // col (src per CSR slot) [3*NE]
constexpr size_t IO_RANK = IO_CL + 3 * NE;       // per-edge rank within dst [3*NE]
constexpr size_t IO_END  = IO_RANK + 3 * NE;
// fp16 activation side-channel (R2: GEMMs are bytes-bound; fp32 x was read 3-4x/layer)
constexpr size_t OFF_X16U = OFF_INT + IO_END;                   // x16 user fp16 [NUSER*128]
constexpr size_t OFF_X16N = OFF_X16U + (size_t)NUSER * 64;      // x16 news fp16

__device__ __forceinline__ float gelu_f(float x) {
    return 0.5f * x * (1.0f + erff(x * 0.70710678118654752440f));
}

// ---------------- swizzled-fragment dest index ----------------
// MFMA 16x16x32 fragment (lane,j): idx = lane&15, k = (lane>>4)*8 + j.
// Wf layout: [kt][ct][lane][j] contiguous -> coalesced b128 stage, conflict-free ds_read_b128.
__device__ __forceinline__ int frag_dest(int k, int col) {
    int kt = k >> 5, quad = (k >> 3) & 3, j = k & 7;
    int ct = col >> 4, m = col & 15;
    int lane = quad * 16 + m;
    return ((kt * 8 + ct) * 64 + lane) * 8 + j;
}

// ---------------- flat weight prep (both layers) + counter zeroing, one dispatch ----------------
constexpr int NEFF = 2 * 2 * 3 * 16384;   // 196608
constexpr int NCVT = 2 * 4 * 16384;       // 131072
constexpr int NBIA = 2 * 2 * 3 * 128;     // 1536
constexpr int NPREP = NEFF + NCVT + NBIA;

__global__ __launch_bounds__(256) void prep_weights_kernel(
    const float* __restrict__ Wk, const float* __restrict__ bk,
    const float* __restrict__ Wv, const float* __restrict__ bv,
    const float* __restrict__ Wq, const float* __restrict__ Wa,
    const float* __restrict__ a_rel, const float* __restrict__ m_rel,
    const float* __restrict__ p_rel,
    _Float16* __restrict__ wkf, float* __restrict__ bke,
    _Float16* __restrict__ wvf, float* __restrict__ bve,
    _Float16* __restrict__ wqf, _Float16* __restrict__ waf,
    int* __restrict__ cu)
{
    const float kscale = 0.17677669529663688f * 1.44269504088896340f;  // 1/sqrt(32)*log2(e)
    int idx = blockIdx.x * 256 + threadIdx.x;
    if (idx < NEFF) {
        int o = idx & 16383;
        int g = idx >> 14;          // (l*2+kind)*3 + r
        int r = g % 3, lk = g / 3, kind = lk & 1, l = lk >> 1;
        int st = (r == 1) ? 1 : 0;
        const float* W   = (kind ? Wv : Wk) + ((size_t)(l * 2 + st)) * 16384;
        const float* rel = (kind ? m_rel : a_rel) + ((size_t)(l * 3 + r)) * 4096;
        _Float16* Wf = (kind ? wvf : wkf) + ((size_t)(l * 3 + r)) * 16384;
        int k = o >> 7, col = o & 127, h = col >> 5, e = col & 31;
        const float* wrow = W + (size_t)k * 128 + h * 32;
        const float* rcol = rel + h * 1024 + e;
        float s = 0.f;
        #pragma unroll
        for (int d = 0; d < 32; ++d) s += wrow[d] * rcol[d * 32];
        if (kind == 0) s *= p_rel[(l * 3 + r) * 4 + h] * kscale;
        Wf[frag_dest(k, col)] = (_Float16)s;
    } else if (idx < NEFF + NCVT) {
        int t = idx - NEFF;
        int o = t & 16383;
        int b = t >> 14;            // l*4 + sub  (sub 0,1: Wq types; 2,3: Wa types)
        int l = b >> 2, sub = b & 3;
        const float* W;
        _Float16* Wf;
        if (sub < 2) { W = Wq + ((size_t)(l * 2 + sub)) * 16384;     Wf = wqf + ((size_t)(l * 2 + sub)) * 16384; }
        else         { W = Wa + ((size_t)(l * 2 + sub - 2)) * 16384; Wf = waf + ((size_t)(l * 2 + sub - 2)) * 16384; }
        int k = o >> 7, col = o & 127;
        Wf[frag_dest(k, col)] = (_Float16)W[o];
    } else if (idx < NPREP) {
        int t = idx - NEFF - NCVT;
        int col = t & 127;
        int g = t >> 7;
        int r = g % 3, lk = g / 3, kind = lk & 1, l = lk >> 1;
        int st = (r == 1) ? 1 : 0;
        const float* bi  = (kind ? bv : bk) + ((size_t)(l * 2 + st)) * 128;
        const float* rel = (kind ? m_rel : a_rel) + ((size_t)(l * 3 + r)) * 4096;
        float* be = (kind ? bve : bke) + (size_t)l * 384 + r * 128;
        int h = col >> 5, e = col & 31;
        float s = 0.f;
        #pragma unroll
        for (int d = 0; d < 32; ++d) s += bi[h * 32 + d] * rel[h * 1024 + d * 32 + e];
        if (kind == 0) s *= p_rel[(l * 3 + r) * 4 + h] * kscale;
        be[col] = s;
    } else if (idx < NPREP + NTOT) {
        cu[idx - NPREP] = 0;       // zero the CSR counters (fused: saves a dispatch)
    }
}

// ---------------- CSR build: hist + per-edge rank (atomics), scan, atomic-free fill ----------------
__global__ void histrank_kernel(const int* __restrict__ e0, const int* __restrict__ e1,
                                const int* __restrict__ e2, int* __restrict__ cu,
                                int* __restrict__ rank) {
    int idx = blockIdx.x * 256 + threadIdx.x;
    if (idx >= 3 * NE) return;
    int r = idx / NE, e = idx - r * NE;
    const int* ei = (r == 0) ? e0 : (r == 1) ? e1 : e2;
    int base = (r == 0) ? 0 : (r == 1) ? NNEWS : (NNEWS + NUSER);
    rank[idx] = atomicAdd(&cu[base + ei[NE + e]], 1);
}

__global__ __launch_bounds__(256) void scan_part_kernel(const int* __restrict__ cu,
                                                        int* __restrict__ bsum) {
    int i = blockIdx.x * 256 + threadIdx.x;
    int v = (i < NTOT) ? cu[i] : 0;
    #pragma unroll
    for (int o = 1; o < 64; o <<= 1) v += __shfl_xor(v, o);
    __shared__ int ws_[4];
    if ((threadIdx.x & 63) == 0) ws_[threadIdx.x >> 6] = v;
    __syncthreads();
    if (threadIdx.x == 0) bsum[blockIdx.x] = ws_[0] + ws_[1] + ws_[2] + ws_[3];
}

__global__ __launch_bounds__(1024) void scan_top_kernel(const int* __restrict__ bsum,
                                                        int* __restrict__ boff,
                                                        int* __restrict__ jrp) {
    __shared__ int wsum[16];
    int tid = threadIdx.x, lane = tid & 63, w = tid >> 6;
    int v = (tid < NSB) ? bsum[tid] : 0;
    int x = v;
    #pragma unroll
    for (int o = 1; o < 64; o <<= 1) { int y = __shfl_up(x, o); if (lane >= o) x += y; }
    if (lane == 63) wsum[w] = x;
    __syncthreads();
    if (tid < 16) {
        int t = wsum[tid];
        #pragma unroll
        for (int o = 1; o < 16; o <<= 1) { int y = __shfl_up(t, o); if (tid >= o) t += y; }
        wsum[tid] = t;
    }
    __syncthreads();
    int woff = w ? wsum[w - 1] : 0;
    if (tid < NSB) boff[tid] = woff + x - v;
    if (tid == 0) jrp[NTOT] = 3 * NE;
}

__global__ __launch_bounds__(256) void scan_fin_kernel(const int* __restrict__ cu,
                                                       const int* __restrict__ boff,
                                                       int* __restrict__ jrp) {
    __shared__ int wsum[4];
    int tid = threadIdx.x, lane = tid & 63, w = tid >> 6;
    int i = blockIdx.x * 256 + tid;
    int v = (i < NTOT) ? cu[i] : 0;
    int x = v;
    #pragma unroll
    for (int o = 1; o < 64; o <<= 1) { int y = __shfl_up(x, o); if (lane >= o) x += y; }
    if (lane == 63) wsum[w] = x;
    __syncthreads();
    int woff = 0;
    #pragma unroll
    for (int k = 0; k < 4; ++k) if (k < w) woff += wsum[k];
    int excl = boff[blockIdx.x] + woff + x - v;
    if (i < NTOT) jrp[i] = excl;
}

__global__ void fill_kernel(const int* __restrict__ e0, const int* __restrict__ e1,
                            const int* __restrict__ e2, const int* __restrict__ jrp,
                            const int* __restrict__ rank, int* __restrict__ cl) {
    int idx = blockIdx.x * 256 + threadIdx.x;
    if (idx >= 3 * NE) return;
    int r = idx / NE, e = idx - r * NE;
    const int* ei = (r == 0) ? e0 : (r == 1) ? e1 : e2;
    int base = (r == 0) ? 0 : (r == 1) ? NNEWS : (NNEWS + NUSER);
    int dst = ei[NE + e], src = ei[e];
    cl[jrp[base + dst] + rank[idx]] = src;   // no atomics (R8: fill3 = 46 us of atomic latency)
}

// ---------------- MFMA GEMM v6: LDS weights, pipelined tiles, fp16 activation paths ----------------
// R2: GEMMs are BYTES-bound (per tile: 2600cy of x-bytes vs 420cy of MFMA at fp32 -> prefetch
// couldn't help). v6 adds:
//  - XOLD_HALF: skip-path residual read as fp16
//  - WRITE_X16: dual-write the fp16-converted x (layer-0 q GEMM populates the x16 side-channel)
//  - out0/out1/Xold are NOT __restrict__ (layer-0 epilogue writes Xold's buffer in-place;
//    per-lane read-before-write on identical channels, disjoint rows across threads)
template<int NOUT, int T, bool IN_HALF, bool GELU_IN, bool SKIP_OUT, bool OUT_HALF,
         bool XOLD_HALF, bool WRITE_X16>
__global__ __launch_bounds__(256) void gemm_v6(
    const void* __restrict__ Ain,
    const _Float16* __restrict__ Wf0, const _Float16* __restrict__ Wf1,
    const float* __restrict__ b0, const float* __restrict__ b1,
    void* out0, void* out1, int ostride,
    int N, const float* __restrict__ skipv, const void* Xold,
    _Float16* x16out)
{
    __shared__ _Float16 sW[NOUT * 16384];   // 32 KB per weight matrix
    const int tid = threadIdx.x;
    const int lane = tid & 63;
    const int m = lane & 15, quad = lane >> 4, wave = tid >> 6;
    const int base_row = blockIdx.x * T * 64;

    // named double buffers (never runtime-indexed -> stay in VGPRs)
    f32x4 xc32_0, xc32_1, xc32_2, xc32_3, xc32_4, xc32_5, xc32_6, xc32_7;
    f32x4 xn32_0, xn32_1, xn32_2, xn32_3, xn32_4, xn32_5, xn32_6, xn32_7;
    f16x8 xc16_0, xc16_1, xc16_2, xc16_3;
    f16x8 xn16_0, xn16_1, xn16_2, xn16_3;

#define LOADX_NEXT(tt)                                                              \
    do {                                                                            \
        int node_ = base_row + (tt) * 64 + wave * 16 + m;                           \
        if (node_ > N - 1) node_ = N - 1;                                           \
        if constexpr (IN_HALF) {                                                    \
            const _Float16* A_ = (const _Float16*)Ain + (size_t)node_ * 128 + quad * 8; \
            xn16_0 = *(const f16x8*)(A_);                                           \
            xn16_1 = *(const f16x8*)(A_ + 32);                                      \
            xn16_2 = *(const f16x8*)(A_ + 64);                                      \
            xn16_3 = *(const f16x8*)(A_ + 96);                                      \
        } else {                                                                    \
            const float* A_ = (const float*)Ain + (size_t)node_ * 128 + quad * 8;   \
            xn32_0 = *(const f32x4*)(A_);        xn32_1 = *(const f32x4*)(A_ + 4);  \
            xn32_2 = *(const f32x4*)(A_ + 32);   xn32_3 = *(const f32x4*)(A_ + 36); \
            xn32_4 = *(const f32x4*)(A_ + 64);   xn32_5 = *(const f32x4*)(A_ + 68); \
            xn32_6 = *(const f32x4*)(A_ + 96);   xn32_7 = *(const f32x4*)(A_ + 100);\
        }                                                                           \
    } while (0)

#define ROTATE_X()                                                                  \
    do {                                                                            \
        if constexpr (IN_HALF) {                                                    \
            xc16_0 = xn16_0; xc16_1 = xn16_1; xc16_2 = xn16_2; xc16_3 = xn16_3;     \
        } else {                                                                    \
            xc32_0 = xn32_0; xc32_1 = xn32_1; xc32_2 = xn32_2; xc32_3 = xn32_3;     \
            xc32_4 = xn32_4; xc32_5 = xn32_5; xc32_6 = xn32_6; xc32_7 = xn32_7;     \
        }                                                                           \
    } while (0)

    // tile-0 x prefetch, issued before LDS staging so HBM latency hides under it
    LOADX_NEXT(0);
    ROTATE_X();

    for (int i = tid; i < NOUT * 2048; i += 256) {
        const _Float16* src = (NOUT == 1 || i < 2048) ? (Wf0 + (size_t)i * 8)
                                                      : (Wf1 + (size_t)(i - 2048) * 8);
        *(f16x8*)(sW + (size_t)i * 8) = *(const f16x8*)src;
    }
    __syncthreads();

    float aS = 0.f, bSk = 0.f;
    if constexpr (SKIP_OUT) {
        float sv = skipv[0];
        aS = 1.0f / (1.0f + expf(-sv));
        bSk = 1.0f - aS;
    }

    #pragma unroll
    for (int t = 0; t < T; ++t) {
        const int row0 = base_row + t * 64;
        if (row0 >= N) break;                       // block-uniform (no barriers inside)
        const int node  = row0 + wave * 16 + m;
        const int nodec = (node < N) ? node : (N - 1);

        // issue NEXT tile's x loads before this tile's compute
        if (t + 1 < T) LOADX_NEXT(t + 1);

        // skip-path residual, loaded early so it completes under the MFMAs.
        // Kept in raw form (f16x4 or f32x4); converted only in the epilogue so no
        // VALU dependency blocks the MFMA issue.
        f32x4 xo0, xo1, xo2, xo3, xo4, xo5, xo6, xo7;
        f16x4 xh0, xh1, xh2, xh3, xh4, xh5, xh6, xh7;
        if constexpr (SKIP_OUT) {
            if constexpr (XOLD_HALF) {
                const _Float16* Xo = (const _Float16*)Xold + (size_t)nodec * 128 + quad * 4;
                xh0 = *(const f16x4*)(Xo);        xh1 = *(const f16x4*)(Xo + 16);
                xh2 = *(const f16x4*)(Xo + 32);   xh3 = *(const f16x4*)(Xo + 48);
                xh4 = *(const f16x4*)(Xo + 64);   xh5 = *(const f16x4*)(Xo + 80);
                xh6 = *(const f16x4*)(Xo + 96);   xh7 = *(const f16x4*)(Xo + 112);
            } else {
                const float* Xo = (const float*)Xold + (size_t)nodec * 128 + quad * 4;
                xo0 = *(const f32x4*)(Xo);       xo1 = *(const f32x4*)(Xo + 16);
                xo2 = *(const f32x4*)(Xo + 32);  xo3 = *(const f32x4*)(Xo + 48);
                xo4 = *(const f32x4*)(Xo + 64);  xo5 = *(const f32x4*)(Xo + 80);
                xo6 = *(const f32x4*)(Xo + 96);  xo7 = *(const f32x4*)(Xo + 112);
            }
        }

        // convert current x to MFMA B-frags
        f16x8 xf[4];
        if constexpr (IN_HALF) {
            xf[0] = xc16_0; xf[1] = xc16_1; xf[2] = xc16_2; xf[3] = xc16_3;
            if constexpr (GELU_IN) {
                #pragma unroll
                for (int kt = 0; kt < 4; ++kt)
                    #pragma unroll
                    for (int j = 0; j < 8; ++j) xf[kt][j] = (_Float16)gelu_f((float)xf[kt][j]);
            }
        } else {
            f32x4 a0[4] = {xc32_0, xc32_2, xc32_4, xc32_6};
            f32x4 a1[4] = {xc32_1, xc32_3, xc32_5, xc32_7};
            #pragma unroll
            for (int kt = 0; kt < 4; ++kt) {
                f32x4 u = a0[kt], v = a1[kt];
                if constexpr (GELU_IN) {
                    #pragma unroll
                    for (int j = 0; j < 4; ++j) { u[j] = gelu_f(u[j]); v[j] = gelu_f(v[j]); }
                }
                xf[kt] = (f16x8){(_Float16)u[0], (_Float16)u[1], (_Float16)u[2], (_Float16)u[3],
                                 (_Float16)v[0], (_Float16)v[1], (_Float16)v[2], (_Float16)v[3]};
            }
        }

        // fp16 activation side-channel: persist the converted x (layer-0 q GEMMs)
        if constexpr (WRITE_X16) {
            if (node < N) {
                _Float16* xd = x16out + (size_t)node * 128 + quad * 8;
                *(f16x8*)(xd)      = xf[0];
                *(f16x8*)(xd + 32) = xf[1];
                *(f16x8*)(xd + 64) = xf[2];
                *(f16x8*)(xd + 96) = xf[3];
            }
        }

        f32x4 acc0[8], acc1[8];
        #pragma unroll
        for (int u = 0; u < 8; ++u) {
            acc0[u] = (f32x4){0.f, 0.f, 0.f, 0.f};
            if constexpr (NOUT > 1) acc1[u] = (f32x4){0.f, 0.f, 0.f, 0.f};
        }

        #pragma unroll
        for (int kt = 0; kt < 4; ++kt) {
            #pragma unroll
            for (int ct = 0; ct < 8; ++ct) {
                f16x8 wf0 = *(const f16x8*)(sW + ((kt * 8 + ct) * 64 + lane) * 8);
                acc0[ct] = __builtin_amdgcn_mfma_f32_16x16x32_f16(wf0, xf[kt], acc0[ct], 0, 0, 0);
                if constexpr (NOUT > 1) {
                    f16x8 wf1 = *(const f16x8*)(sW + 16384 + ((kt * 8 + ct) * 64 + lane) * 8);
                    acc1[ct] = __builtin_amdgcn_mfma_f32_16x16x32_f16(wf1, xf[kt], acc1[ct], 0, 0, 0);
                }
            }
        }

        if (node < N) {
            f32x4 xoa[8];
            if constexpr (SKIP_OUT) {
                if constexpr (XOLD_HALF) {
                    f16x4 xhh[8] = {xh0, xh1, xh2, xh3, xh4, xh5, xh6, xh7};
                    #pragma unroll
                    for (int ct = 0; ct < 8; ++ct)
                        xoa[ct] = (f32x4){(float)xhh[ct][0], (float)xhh[ct][1],
                                          (float)xhh[ct][2], (float)xhh[ct][3]};
                } else {
                    xoa[0] = xo0; xoa[1] = xo1; xoa[2] = xo2; xoa[3] = xo3;
                    xoa[4] = xo4; xoa[5] = xo5; xoa[6] = xo6; xoa[7] = xo7;
                }
            }
            #pragma unroll
            for (int ct = 0; ct < 8; ++ct) {
                int c = ct * 16 + quad * 4;      // out-channel base for this lane's 4 regs
                {
                    f32x4 r = acc0[ct] + *(const f32x4*)(b0 + c);
                    if constexpr (SKIP_OUT) {
                        #pragma unroll
                        for (int j = 0; j < 4; ++j) r[j] = fmaxf(aS * r[j] + bSk * xoa[ct][j], 0.f);
                    }
                    if constexpr (OUT_HALF) {
                        f16x4 h = {(_Float16)r[0], (_Float16)r[1], (_Float16)r[2], (_Float16)r[3]};
                        *(f16x4*)((_Float16*)out0 + (size_t)node * ostride + c) = h;
                    } else {
                        *(f32x4*)((float*)out0 + (size_t)node * ostride + c) = r;
                    }
                }
                if constexpr (NOUT > 1) {
                    f32x4 r = acc1[ct] + *(const f32x4*)(b1 + c);
                    f16x4 h = {(_Float16)r[0], (_Float16)r[1], (_Float16)r[2], (_Float16)r[3]};
                    *(f16x4*)((_Float16*)out1 + (size_t)node * ostride + c) = h;
                }
            }
        }

        if (t + 1 < T) ROTATE_X();
    }
#undef LOADX_NEXT
#undef ROTATE_X
}

// ---------------- attention v5 (kept: v6 4-slot unroll regressed; VALU-issue-bound ~64%) -------
// kv interleaved [node][k|v] fp16. Lane sub (0..15): channels sub*8..+7, head = sub>>2.
// w = exp2(score) (log2e folded into k_eff). agg := gelu(softmax-agg)  [epilogue GEMM eats it raw].
__global__ __launch_bounds__(256) void attn_v5(
    const _Float16* __restrict__ q,
    const _Float16* __restrict__ kv1, const int* __restrict__ rp1,
    const _Float16* __restrict__ kv2, const int* __restrict__ rp2,
    const int* __restrict__ cl,
    _Float16* __restrict__ agg, int Ndst, int two)
{
    int d = blockIdx.x * 16 + (threadIdx.x >> 4);   // 16 nodes per block (4 per wave)
    if (d >= Ndst) return;
    const int sub = threadIdx.x & 15;
    f16x8 qh = *(const f16x8*)(q + (size_t)d * 128 + sub * 8);
    float acc[8] = {0.f, 0.f, 0.f, 0.f, 0.f, 0.f, 0.f, 0.f};

    for (int rel = 0; rel < 1 + two; ++rel) {
        const _Float16* kv = rel ? kv2 : kv1;
        const int* rp = rel ? rp2 : rp1;
        int e0 = rp[d], e1 = rp[d + 1];
        float den = 0.f;
        float s[8] = {0.f, 0.f, 0.f, 0.f, 0.f, 0.f, 0.f, 0.f};
        int e = e0;
        for (; e + 1 < e1; e += 2) {                // two independent chains per iter
            int s0 = cl[e], s1 = cl[e + 1];
            const _Float16* r0 = kv + (size_t)s0 * 256;
            const _Float16* r1 = kv + (size_t)s1 * 256;
            f16x8 k0 = *(const f16x8*)(r0 + sub * 8);
            f16x8 v0 = *(const f16x8*)(r0 + 128 + sub * 8);
            f16x8 k1 = *(const f16x8*)(r1 + sub * 8);
            f16x8 v1 = *(const f16x8*)(r1 + 128 + sub * 8);
            float p0 = 0.f, p1 = 0.f;
#if __has_builtin(__builtin_amdgcn_fdot2)
            const f16x2* qp = (const f16x2*)&qh;
            const f16x2* a0 = (const f16x2*)&k0;
            const f16x2* a1 = (const f16x2*)&k1;
            #pragma unroll
            for (int j = 0; j < 4; ++j) {
                p0 = __builtin_amdgcn_fdot2(a0[j], qp[j], p0, false);
                p1 = __builtin_amdgcn_fdot2(a1[j], qp[j], p1, false);
            }
#else
            #pragma unroll
            for (int j = 0; j < 8; ++j) {
                p0 += (float)k0[j] * (float)qh[j];
                p1 += (float)k1[j] * (float)qh[j];
            }
#endif
            p0 += __shfl_xor(p0, 1); p1 += __shfl_xor(p1, 1);
            p0 += __shfl_xor(p0, 2); p1 += __shfl_xor(p1, 2);
            float w0 = exp2f(p0), w1 = exp2f(p1);
            den += w0 + w1;
            #pragma unroll
            for (int j = 0; j < 8; ++j) s[j] += w0 * (float)v0[j] + w1 * (float)v1[j];
        }
        if (e < e1) {
            int s0 = cl[e];
            const _Float16* r0 = kv + (size_t)s0 * 256;
            f16x8 k0 = *(const f16x8*)(r0 + sub * 8);
            f16x8 v0 = *(const f16x8*)(r0 + 128 + sub * 8);
            float p0 = 0.f;
#if __has_builtin(__builtin_amdgcn_fdot2)
            const f16x2* qp = (const f16x2*)&qh;
            const f16x2* a0 = (const f16x2*)&k0;
            #pragma unroll
            for (int j = 0; j < 4; ++j) p0 = __builtin_amdgcn_fdot2(a0[j], qp[j], p0, false);
#else
            #pragma unroll
            for (int j = 0; j < 8; ++j) p0 += (float)k0[j] * (float)qh[j];
#endif
            p0 += __shfl_xor(p0, 1);
            p0 += __shfl_xor(p0, 2);
            float w0 = exp2f(p0);
            den += w0;
            #pragma unroll
            for (int j = 0; j < 8; ++j) s[j] += w0 * (float)v0[j];
        }
        if (den > 0.f) {
            float inv = 1.f / den;
            #pragma unroll
            for (int j = 0; j < 8; ++j) acc[j] += s[j] * inv;
        }
    }

    f16x8 o;
    #pragma unroll
    for (int j = 0; j < 8; ++j) o[j] = (_Float16)gelu_f(acc[j]);   // gelu fused (epilogue is pure MFMA)
    *(f16x8*)(agg + (size_t)d * 128 + sub * 8) = o;
}

// ---------------- orchestration ----------------
extern "C" void kernel_launch(void* const* d_in, const int* in_sizes, int n_in,
                              void* d_out, int out_size, void* d_ws, size_t ws_size,
                              hipStream_t stream)
{
    const float* x_user = (const float*)d_in[0];
    const float* x_news = (const float*)d_in[1];
    const int* ei0 = (const int*)d_in[2];
    const int* ei1 = (const int*)d_in[3];
    const int* ei2 = (const int*)d_in[4];
    const float* Wk = (const float*)d_in[5];
    const float* bk = (const float*)d_in[6];
    const float* Wq = (const float*)d_in[7];
    const float* bq = (const float*)d_in[8];
    const float* Wv = (const float*)d_in[9];
    const float* bv = (const float*)d_in[10];
    const float* Wa = (const float*)d_in[11];
    const float* ba = (const float*)d_in[12];
    const float* skip = (const float*)d_in[13];
    const float* a_rel = (const float*)d_in[14];
    const float* m_rel = (const float*)d_in[15];
    const float* p_rel = (const float*)d_in[16];

    float* ws = (float*)d_ws;
    _Float16* q_user  = (_Float16*)(ws + OFF_QU);
    _Float16* q_news  = (_Float16*)(ws + OFF_QN);
    _Float16* agg_u   = (_Float16*)(ws + OFF_AGU);
    _Float16* agg_n   = (_Float16*)(ws + OFF_AGN);
    _Float16* kv_big  = (_Float16*)(ws + OFF_KVB);
    _Float16* kv_sm   = (_Float16*)(ws + OFF_KVS);
    _Float16* wkf = (_Float16*)(ws + OFF_WF);       // [2][3] matrices
    _Float16* wvf = wkf + 6 * 16384;                // [2][3]
    _Float16* wqf = wvf + 6 * 16384;                // [2][2]
    _Float16* waf = wqf + 4 * 16384;                // [2][2]
    float* bke = ws + OFF_BE;                       // [2][3][128]
    float* bve = bke + 768;
    int* ib   = (int*)(ws + OFF_INT);
    int* cu   = ib + IO_CU;
    int* jrp  = ib + IO_JRP;
    int* bsum = ib + IO_BSUM;
    int* boff = ib + IO_BOFF;
    int* cl   = ib + IO_CL;
    int* rank = ib + IO_RANK;
    _Float16* x16u = (_Float16*)(ws + OFF_X16U);    // fp16 activation side-channel
    _Float16* x16n = (_Float16*)(ws + OFF_X16N);
    const int* rp0 = jrp;
    const int* rp1 = jrp + NNEWS;
    const int* rp2 = jrp + NNEWS + NUSER;

    // ---- weight prep (both layers) + counter zero, one flat dispatch ----
    prep_weights_kernel<<<(NPREP + NTOT + 255) / 256, 256, 0, stream>>>(
        Wk, bk, Wv, bv, Wq, Wa, a_rel, m_rel, p_rel,
        wkf, bke, wvf, bve, wqf, waf, cu);

    // ---- CSR build: hist+rank (atomics) -> scan -> atomic-free fill ----
    int g3e = (3 * NE + 255) / 256;
    histrank_kernel<<<g3e, 256, 0, stream>>>(ei0, ei1, ei2, cu, rank);
    scan_part_kernel<<<NSB, 256, 0, stream>>>(cu, bsum);
    scan_top_kernel<<<1, 1024, 0, stream>>>(bsum, boff, jrp);
    scan_fin_kernel<<<NSB, 256, 0, stream>>>(cu, boff, jrp);
    fill_kernel<<<g3e, 256, 0, stream>>>(ei0, ei1, ei2, jrp, rank, cl);

    float* out_user = (float*)d_out;
    float* out_news = (float*)d_out + (size_t)NUSER * CH;

    constexpr int T1 = 2;   // NOUT=1 user GEMMs: 782 blocks (~3/CU)
    constexpr int T2 = 4;   // NOUT=2 user GEMMs: 64KB LDS caps 2 blocks/CU anyway
    int gbU1 = (NUSER + 64 * T1 - 1) / (64 * T1);
    int gbU2 = (NUSER + 64 * T2 - 1) / (64 * T2);
    int gbN  = (NNEWS + 63) / 64;                  // news: T=1 (keep TLP)

    for (int l = 0; l < 2; ++l) {
        _Float16* wkf_l = wkf + (size_t)l * 3 * 16384;
        _Float16* wvf_l = wvf + (size_t)l * 3 * 16384;
        _Float16* wqf_l = wqf + (size_t)l * 2 * 16384;
        _Float16* waf_l = waf + (size_t)l * 2 * 16384;
        float* bke_l = bke + (size_t)l * 384;
        float* bve_l = bve + (size_t)l * 384;

        // q projections (fp16 out). Layer 0 reads fp32 inputs and dual-writes the fp16
        // x16 side-channel; layer 1 reads the fp16 activations directly.
        if (l == 0) {
            gemm_v6<1, T1, false, false, false, true, false, true><<<gbU1, 256, 0, stream>>>(
                x_user, wqf_l, nullptr, bq + (size_t)0 * 128, nullptr,
                q_user, nullptr, 128, NUSER, nullptr, nullptr, x16u);
            gemm_v6<1, 1, false, false, false, true, false, true><<<gbN, 256, 0, stream>>>(
                x_news, wqf_l + 16384, nullptr, bq + (size_t)1 * 128, nullptr,
                q_news, nullptr, 128, NNEWS, nullptr, nullptr, x16n);
        } else {
            gemm_v6<1, T1, true, false, false, true, false, false><<<gbU1, 256, 0, stream>>>(
                x16u, wqf_l, nullptr, bq + (size_t)2 * 128, nullptr,
                q_user, nullptr, 128, NUSER, nullptr, nullptr, nullptr);
            gemm_v6<1, 1, true, false, false, true, false, false><<<gbN, 256, 0, stream>>>(
                x16n, wqf_l + 16384, nullptr, bq + (size_t)3 * 128, nullptr,
                q_news, nullptr, 128, NNEWS, nullptr, nullptr, nullptr);
        }

        // rel0 K/V (user src) -> kv_big, then news attention (all x reads fp16 now)
        gemm_v6<2, T2, true, false, false, true, false, false><<<gbU2, 256, 0, stream>>>(
            x16u, wkf_l, wvf_l, bke_l, bve_l,
            kv_big, kv_big + 128, 256, NUSER, nullptr, nullptr, nullptr);
        attn_v5<<<(NNEWS + 15) / 16, 256, 0, stream>>>(
            q_news, kv_big, rp0, nullptr, nullptr, cl, agg_n, NNEWS, 0);

        // rel1 K/V (news src) -> kv_sm ; rel2 K/V (user src) -> kv_big (reuse, stream-ordered)
        gemm_v6<2, 1, true, false, false, true, false, false><<<gbN, 256, 0, stream>>>(
            x16n, wkf_l + 16384, wvf_l + 16384, bke_l + 128, bve_l + 128,
            kv_sm, kv_sm + 128, 256, NNEWS, nullptr, nullptr, nullptr);
        gemm_v6<2, T2, true, false, false, true, false, false><<<gbU2, 256, 0, stream>>>(
            x16u, wkf_l + 32768, wvf_l + 32768, bke_l + 256, bve_l + 256,
            kv_big, kv_big + 128, 256, NUSER, nullptr, nullptr, nullptr);
        attn_v5<<<(NUSER + 15) / 16, 256, 0, stream>>>(
            q_user, kv_sm, rp1, kv_big, rp2, cl, agg_u, NUSER, 1);

        // output transform: relu(sig(skip)*(gelu_agg@Wa + ba) + (1-sig)*x)
        // Layer 0: Xold = x16 (fp16 rounded input), write fp16 IN-PLACE into x16 ->
        //          layer 1 reads it as its activation. Layer 1: Xold = x16, write fp32 d_out.
        if (l == 0) {
            gemm_v6<1, T1, true, false, true, true, true, false><<<gbU1, 256, 0, stream>>>(
                agg_u, waf_l, nullptr, ba + (size_t)0 * 128, nullptr,
                x16u, nullptr, 128, NUSER, skip + 0, x16u, nullptr);
            gemm_v6<1, 1, true, false, true, true, true, false><<<gbN, 256, 0, stream>>>(
                agg_n, waf_l + 16384, nullptr, ba + (size_t)1 * 128, nullptr,
                x16n, nullptr, 128, NNEWS, skip + 1, x16n, nullptr);
        } else {
            gemm_v6<1, T1, true, false, true, false, true, false><<<gbU1, 256, 0, stream>>>(
                agg_u, waf_l, nullptr, ba + (size_t)2 * 128, nullptr,
                out_user, nullptr, 128, NUSER, skip + 2, x16u, nullptr);
            gemm_v6<1, 1, true, false, true, false, true, false><<<gbN, 256, 0, stream>>>(
                agg_n, waf_l + 16384, nullptr, ba + (size_t)3 * 128, nullptr,
                out_news, nullptr, 128, NNEWS, skip + 3, x16n, nullptr);
        }
    }
    (void)in_sizes; (void)n_in; (void)out_size; (void)ws_size;
}